// Round 8
// baseline (188.785 us; speedup 1.0000x reference)
//
#include <hip/hip_runtime.h>
#include <cstddef>

// Depthwise 7x7 conv, stride 1, pad 3, 4-fold rotational kernel symmetrization.
// x: [16,384,64,64] fp32, w: [384,1,7,7] fp32, out: [16,384,64,64] fp32.
//
// R9: SOFTWARE-PIPELINED MULTI-PLANE WAVES (ILP across planes, not TLP).
// Ledger: dur pinned at 63-66us across 5 structures and 3 launch configs,
// always VALUBusy ~31-36% = (total VALU work ~20us)/(dur). R8 falsified the
// launch-bounds-cap theory: no attribute, same 104 VGPR, same 17% occupancy.
// Diagnosis: TLP never materializes; every block pays its 14-load cold burst
// (~900cy) once per 3400cy of compute and dies -- 3072 tiny blocks = 3072
// exposed latencies. Fix: each wave processes ITER=4 planes with DOUBLE-
// BUFFERED register prefetch -- while computing plane k from rA, plane k+2's
// loads fly into rB's sibling; each 3400cy compute covers the next ~900cy
// load latency 3.8x over, independent of residency. Prologue latency is the
// only exposed stall: ~6% of the wave's 13.9Kcy work.
//  - Loop form (2 compute bodies, A/B by parity, #pragma unroll 1 outer):
//    ~25KB code, fits 32KB L1I. All array indices compile-time (rule #20).
//  - One-arg __launch_bounds__(128): R6/R8 lesson -- any waves-per-EU value
//    both caps residency AND squeezes the allocator into spills. Natural
//    allocation ~190 VGPR, no cap -> no spill (R3/R6 spills were cap-induced).
//  - Body per plane unchanged from R5-R8: zero-LDS, one global_load_dwordx4
//    per input row, DPP halo exchange (bound_ctrl=1 zeroes at 16-lane rows
//    == image col edges), 1568 FMA, 8 dense float4 stores.
//  - plane is block-uniform now (no readfirstlane needed): weight loads are
//    scalar automatically; next plane's weights prefetch under compute.

#define BLOCK 128
#define ITER 4

// --- compile-time C4 orbit table for the symmetrized 7x7 kernel (13 orbits) ---
constexpr int canon_of(int k) {
    const int i = k / 7, j = k % 7;
    const int a = i * 7 + j;
    const int b = j * 7 + (6 - i);
    const int c = (6 - i) * 7 + (6 - j);
    const int d = (6 - j) * 7 + i;
    int m = a;
    if (b < m) m = b;
    if (c < m) m = c;
    if (d < m) m = d;
    return m;
}
struct Tab { int cidx[49]; };
constexpr Tab build_tab() {
    Tab t{};
    int u = 0;
    for (int k = 0; k < 49; ++k)
        if (canon_of(k) == k) { t.cidx[k] = u; ++u; }
    for (int k = 0; k < 49; ++k) t.cidx[k] = t.cidx[canon_of(k)];
    return t;
}
constexpr Tab TAB = build_tab();

// DPP lane shifts within 16-lane rows. bound_ctrl=1: invalid source lane -> 0,
// implementing column-edge zero padding for free (16-lane rows align exactly
// with cg = lane&15 and the 64-col image edges).
__device__ __forceinline__ float dpp_shr1(float v) {   // lane l <- lane l-1
    return __int_as_float(__builtin_amdgcn_update_dpp(
        0, __float_as_int(v), 0x111, 0xF, 0xF, true));
}
__device__ __forceinline__ float dpp_shl1(float v) {   // lane l <- lane l+1
    return __int_as_float(__builtin_amdgcn_update_dpp(
        0, __float_as_int(v), 0x101, 0xF, 0xF, true));
}

// Issue 14 row loads for one plane into a register buffer (addresses clamped;
// OOB rows zeroed at consume time). Fully unrolled: all indices static.
__device__ __forceinline__ void load_rows(float4 (&r)[14],
                                          const float* __restrict__ xp, int y0) {
    #pragma unroll
    for (int m = 0; m < 14; ++m) {
        const int row = y0 - 3 + m;
        const int rr = row < 0 ? 0 : (row > 63 ? 63 : row);
        r[m] = *(const float4*)(xp + rr * 64);
    }
}

// Symmetrized unique weights -> 13 regs (block-uniform -> scalar loads).
__device__ __forceinline__ void load_wu(float (&wu)[13],
                                        const float* __restrict__ wc) {
    #pragma unroll
    for (int k = 0; k < 49; ++k) {
        if (canon_of(k) == k) {
            const int i = k / 7, j = k % 7;
            wu[TAB.cidx[k]] = 0.25f * (wc[i * 7 + j]
                                     + wc[j * 7 + (6 - i)]
                                     + wc[(6 - i) * 7 + (6 - j)]
                                     + wc[(6 - j) * 7 + i]);
        }
    }
}

// Consume one plane's register buffer: DPP halo, 1568 FMA, 8 dense stores.
__device__ __forceinline__ void compute_store(const float4 (&rows)[14],
                                              const float (&wu)[13],
                                              float* __restrict__ ob, int y0) {
    float acc[8][4];
    #pragma unroll
    for (int t = 0; t < 8; ++t)
        #pragma unroll
        for (int d = 0; d < 4; ++d) acc[t][d] = 0.f;

    #pragma unroll
    for (int m = 0; m < 14; ++m) {
        const int row = y0 - 3 + m;
        float4 b = rows[m];
        if ((unsigned)row >= 64u) {          // top/bottom zero padding
            b.x = 0.f; b.y = 0.f; b.z = 0.f; b.w = 0.f;
        }
        const float l1 = dpp_shr1(b.y);      // col x0-3
        const float l2 = dpp_shr1(b.z);      // col x0-2
        const float l3 = dpp_shr1(b.w);      // col x0-1
        const float h4 = dpp_shl1(b.x);      // col x0+4
        const float h5 = dpp_shl1(b.y);      // col x0+5
        const float h6 = dpp_shl1(b.z);      // col x0+6
        // r_[1..10] = cols x0-3 .. x0+6 (indices 0 and 11 never referenced)
        const float r_[12] = {0.f, l1, l2, l3, b.x, b.y, b.z, b.w,
                              h4, h5, h6, 0.f};
        #pragma unroll
        for (int t = 0; t < 8; ++t) {
            if (t <= m && m <= t + 6) {      // constant after unroll
                const int i = m - t;         // kernel row
                #pragma unroll
                for (int d = 0; d < 4; ++d)
                    #pragma unroll
                    for (int j = 0; j < 7; ++j)
                        acc[t][d] += r_[d + j + 1] * wu[TAB.cidx[i * 7 + j]];
            }
        }
    }

    #pragma unroll
    for (int t = 0; t < 8; ++t) {
        float4 v;
        v.x = acc[t][0]; v.y = acc[t][1]; v.z = acc[t][2]; v.w = acc[t][3];
        *(float4*)(ob + t * 64) = v;         // 4x 256B dense aligned segments
    }
}

__global__ __launch_bounds__(BLOCK) void dwconv7_sym_kernel(
    const float* __restrict__ x, const float* __restrict__ w,
    float* __restrict__ out, int C)
{
    const int tid = threadIdx.x;
    const int cg = tid & 15;                 // col strip: cols 4cg..4cg+3
    const int S  = tid >> 4;                 // 0..7: out rows 8S..8S+7
    const int y0 = S << 3;
    const int x0 = cg << 2;
    const int p0 = blockIdx.x * ITER;        // first plane of this block

    float4 rA[14], rB[14];
    float wuA[13], wuB[13];

    // --- prologue: fill both pipeline stages ---
    load_rows(rA, x + (size_t)(p0 + 0) * 4096 + x0, y0);
    load_wu(wuA, w + ((p0 + 0) % C) * 49);
    load_rows(rB, x + (size_t)(p0 + 1) * 4096 + x0, y0);
    load_wu(wuB, w + ((p0 + 1) % C) * 49);

    // --- steady state: compute[k] covers loads[k+2]'s latency ---
    #pragma unroll 1
    for (int it = 0; it < ITER; it += 2) {
        compute_store(rA, wuA, out + (size_t)(p0 + it) * 4096 + y0 * 64 + x0, y0);
        if (it + 2 < ITER) {
            load_rows(rA, x + (size_t)(p0 + it + 2) * 4096 + x0, y0);
            load_wu(wuA, w + ((p0 + it + 2) % C) * 49);
        }
        compute_store(rB, wuB, out + (size_t)(p0 + it + 1) * 4096 + y0 * 64 + x0, y0);
        if (it + 3 < ITER) {
            load_rows(rB, x + (size_t)(p0 + it + 3) * 4096 + x0, y0);
            load_wu(wuB, w + ((p0 + it + 3) % C) * 49);
        }
    }
}

extern "C" void kernel_launch(void* const* d_in, const int* in_sizes, int n_in,
                              void* d_out, int out_size, void* d_ws, size_t ws_size,
                              hipStream_t stream) {
    const float* x = (const float*)d_in[0];
    const float* w = (const float*)d_in[1];
    float* out = (float*)d_out;

    const int planes = in_sizes[0] / 4096;   // N*C = 6144
    const int C = in_sizes[1] / 49;          // 384

    dwconv7_sym_kernel<<<dim3(planes / ITER), dim3(BLOCK), 0, stream>>>(x, w, out, C);
}